// Round 1
// baseline (1054.144 us; speedup 1.0000x reference)
//
#include <hip/hip_runtime.h>
#include <math.h>

#define S 2048
#define DD 2048
#define NH 16
#define DH 128
#define DHID 128
#define DKER 64
#define EPSF 1e-6f

__device__ __forceinline__ float gelu_f(float x) {
    return 0.5f * x * (1.0f + erff(x * 0.7071067811865475f));
}

// Y[h,s,e] = gelu( sum_d X[s, h*128+d] * W[h,d,e] ),  e in [0,128)
__global__ __launch_bounds__(256) void k_mlp1(const float* __restrict__ X,
                                              const float* __restrict__ Wall,
                                              float* __restrict__ Y) {
    const int h = blockIdx.y;
    const int s0 = blockIdx.x * 64;
    const int tid = threadIdx.x;
    const int ty = tid >> 4, tx = tid & 15;  // thread tile: rows ty*4..+3, cols tx*8..+7
    __shared__ float Xs[64][20];   // pad 20: 2-way max conflicts, 80B row stride (16B aligned)
    __shared__ float Ws[16][128];
    const float* Wh = Wall + h * DH * DHID;
    float acc[4][8] = {};

    const int lr = tid >> 2, lc = tid & 3;
    const int wr = tid >> 5, wc = tid & 31;
    for (int kc = 0; kc < 8; ++kc) {
        *(float4*)(&Xs[lr][lc * 4]) =
            *(const float4*)(X + (size_t)(s0 + lr) * DD + h * DH + kc * 16 + lc * 4);
        *(float4*)(&Ws[wr][wc * 4]) =
            *(const float4*)(Wh + (kc * 16 + wr) * DHID + wc * 4);
        *(float4*)(&Ws[wr + 8][wc * 4]) =
            *(const float4*)(Wh + (kc * 16 + wr + 8) * DHID + wc * 4);
        __syncthreads();
        #pragma unroll
        for (int kk = 0; kk < 16; ++kk) {
            float a[4];
            #pragma unroll
            for (int i = 0; i < 4; ++i) a[i] = Xs[ty * 4 + i][kk];
            float4 b0 = *(const float4*)(&Ws[kk][tx * 8]);
            float4 b1 = *(const float4*)(&Ws[kk][tx * 8 + 4]);
            #pragma unroll
            for (int i = 0; i < 4; ++i) {
                acc[i][0] += a[i] * b0.x; acc[i][1] += a[i] * b0.y;
                acc[i][2] += a[i] * b0.z; acc[i][3] += a[i] * b0.w;
                acc[i][4] += a[i] * b1.x; acc[i][5] += a[i] * b1.y;
                acc[i][6] += a[i] * b1.z; acc[i][7] += a[i] * b1.w;
            }
        }
        __syncthreads();
    }
    float* Yp = Y + ((size_t)h * S + s0) * DHID;
    #pragma unroll
    for (int i = 0; i < 4; ++i) {
        float4 o0, o1;
        o0.x = gelu_f(acc[i][0]); o0.y = gelu_f(acc[i][1]);
        o0.z = gelu_f(acc[i][2]); o0.w = gelu_f(acc[i][3]);
        o1.x = gelu_f(acc[i][4]); o1.y = gelu_f(acc[i][5]);
        o1.z = gelu_f(acc[i][6]); o1.w = gelu_f(acc[i][7]);
        *(float4*)(Yp + (ty * 4 + i) * DHID + tx * 8) = o0;
        *(float4*)(Yp + (ty * 4 + i) * DHID + tx * 8 + 4) = o1;
    }
}

// Q2abs[h,s,e] = | gelu( Y1[h,s,:] @ W2[h] ) |,  e in [0,64)
__global__ __launch_bounds__(256) void k_mlp2_q(const float* __restrict__ Y1,
                                                const float* __restrict__ Wall,
                                                float* __restrict__ Q2) {
    const int h = blockIdx.y;
    const int s0 = blockIdx.x * 64;
    const int tid = threadIdx.x;
    const int ty = tid >> 4, tx = tid & 15;  // rows ty*4..+3, cols tx*4..+3
    __shared__ float Ys[64][20];
    __shared__ float Ws[16][64];
    const float* Wh = Wall + h * DHID * DKER;
    float acc[4][4] = {};
    const int lr = tid >> 2, lc = tid & 3;
    const int wr = tid >> 4, wc = tid & 15;
    for (int kc = 0; kc < 8; ++kc) {
        *(float4*)(&Ys[lr][lc * 4]) =
            *(const float4*)(Y1 + ((size_t)h * S + s0 + lr) * DHID + kc * 16 + lc * 4);
        *(float4*)(&Ws[wr][wc * 4]) =
            *(const float4*)(Wh + (kc * 16 + wr) * DKER + wc * 4);
        __syncthreads();
        #pragma unroll
        for (int kk = 0; kk < 16; ++kk) {
            float4 b = *(const float4*)(&Ws[kk][tx * 4]);
            #pragma unroll
            for (int i = 0; i < 4; ++i) {
                float a = Ys[ty * 4 + i][kk];
                acc[i][0] += a * b.x; acc[i][1] += a * b.y;
                acc[i][2] += a * b.z; acc[i][3] += a * b.w;
            }
        }
        __syncthreads();
    }
    float* Qp = Q2 + ((size_t)h * S + s0) * DKER;
    #pragma unroll
    for (int i = 0; i < 4; ++i) {
        float4 o;
        o.x = fabsf(gelu_f(acc[i][0])); o.y = fabsf(gelu_f(acc[i][1]));
        o.z = fabsf(gelu_f(acc[i][2])); o.w = fabsf(gelu_f(acc[i][3]));
        *(float4*)(Qp + (ty * 4 + i) * DKER + tx * 4) = o;
    }
}

// k2 = |sD| * gelu(Y1k @ Wk2); K3abs = | k2 + (k2 @ Ik) * sD2 |
__global__ __launch_bounds__(256) void k_mlp2_k(const float* __restrict__ Y1,
                                                const float* __restrict__ Wall,
                                                const float* __restrict__ Ikall,
                                                const float* __restrict__ sD,
                                                const float* __restrict__ sD2,
                                                float* __restrict__ K3) {
    const int h = blockIdx.y;
    const int s0 = blockIdx.x * 64;
    const int tid = threadIdx.x;
    const int ty = tid >> 4, tx = tid & 15;
    __shared__ float Ys[64][20];
    __shared__ float Ws[16][64];
    __shared__ float K2s[64][68];
    __shared__ float Iks[64][64];
    const float* Wh = Wall + h * DHID * DKER;
    const float* Ikh = Ikall + h * DKER * DKER;
    // stage interaction matrix once
    #pragma unroll
    for (int it = 0; it < 4; ++it) {
        int idx = it * 256 + tid;
        int r = idx >> 4, c = idx & 15;
        *(float4*)(&Iks[r][c * 4]) = *(const float4*)(Ikh + r * DKER + c * 4);
    }
    float acc[4][4] = {};
    const int lr = tid >> 2, lc = tid & 3;
    const int wr = tid >> 4, wc = tid & 15;
    for (int kc = 0; kc < 8; ++kc) {
        *(float4*)(&Ys[lr][lc * 4]) =
            *(const float4*)(Y1 + ((size_t)h * S + s0 + lr) * DHID + kc * 16 + lc * 4);
        *(float4*)(&Ws[wr][wc * 4]) =
            *(const float4*)(Wh + (kc * 16 + wr) * DKER + wc * 4);
        __syncthreads();
        #pragma unroll
        for (int kk = 0; kk < 16; ++kk) {
            float4 b = *(const float4*)(&Ws[kk][tx * 4]);
            #pragma unroll
            for (int i = 0; i < 4; ++i) {
                float a = Ys[ty * 4 + i][kk];
                acc[i][0] += a * b.x; acc[i][1] += a * b.y;
                acc[i][2] += a * b.z; acc[i][3] += a * b.w;
            }
        }
        __syncthreads();
    }
    float sdv[4], sd2v[4];
    #pragma unroll
    for (int j = 0; j < 4; ++j) {
        sdv[j] = fabsf(sD[h * DKER + tx * 4 + j]);
        sd2v[j] = sD2[h * DKER + tx * 4 + j];
    }
    float k2r[4][4];
    #pragma unroll
    for (int i = 0; i < 4; ++i) {
        #pragma unroll
        for (int j = 0; j < 4; ++j) k2r[i][j] = sdv[j] * gelu_f(acc[i][j]);
        float4 o; o.x = k2r[i][0]; o.y = k2r[i][1]; o.z = k2r[i][2]; o.w = k2r[i][3];
        *(float4*)(&K2s[ty * 4 + i][tx * 4]) = o;
    }
    __syncthreads();
    float acc2[4][4] = {};
    #pragma unroll 16
    for (int f = 0; f < 64; ++f) {
        float4 b = *(const float4*)(&Iks[f][tx * 4]);
        #pragma unroll
        for (int i = 0; i < 4; ++i) {
            float a = K2s[ty * 4 + i][f];
            acc2[i][0] += a * b.x; acc2[i][1] += a * b.y;
            acc2[i][2] += a * b.z; acc2[i][3] += a * b.w;
        }
    }
    float* Kp = K3 + ((size_t)h * S + s0) * DKER;
    #pragma unroll
    for (int i = 0; i < 4; ++i) {
        float4 o;
        o.x = fabsf(k2r[i][0] + acc2[i][0] * sd2v[0]);
        o.y = fabsf(k2r[i][1] + acc2[i][1] * sd2v[1]);
        o.z = fabsf(k2r[i][2] + acc2[i][2] * sd2v[2]);
        o.w = fabsf(k2r[i][3] + acc2[i][3] * sd2v[3]);
        *(float4*)(Kp + (ty * 4 + i) * DKER + tx * 4) = o;
    }
}

// invd[h,s] = 1 / ( q2abs[h,s,:] . (sum_t mask[s,t]*k3abs[h,t,:]) + EPS + exp(lse[h,s]) )
__global__ __launch_bounds__(256) void k_rowsum(const float* __restrict__ Q2,
                                                const float* __restrict__ K3,
                                                const int* __restrict__ mask,
                                                const float* __restrict__ lse,
                                                float* __restrict__ invd) {
    const int h = blockIdx.y;
    const int s0 = blockIdx.x * 64;
    const int tid = threadIdx.x;
    const int ty = tid >> 4, tx = tid & 15;  // rows ty*4..+3, dims tx*4..+3
    __shared__ float Ms[64][68];
    __shared__ float Ks[64][68];
    __shared__ float red[64][17];
    float acc[4][4] = {};
    const int lr = tid >> 2 >> 2, dummy = 0; (void)dummy; (void)lr;
    for (int t0 = 0; t0 < S; t0 += 64) {
        #pragma unroll
        for (int it = 0; it < 4; ++it) {
            int idx = it * 256 + tid;
            int r = idx >> 4, c = idx & 15;
            int4 mv = *(const int4*)(mask + (size_t)(s0 + r) * S + t0 + c * 4);
            float4 mf;
            mf.x = mv.x != 0 ? 1.f : 0.f; mf.y = mv.y != 0 ? 1.f : 0.f;
            mf.z = mv.z != 0 ? 1.f : 0.f; mf.w = mv.w != 0 ? 1.f : 0.f;
            *(float4*)(&Ms[r][c * 4]) = mf;
            *(float4*)(&Ks[r][c * 4]) =
                *(const float4*)(K3 + ((size_t)h * S + t0 + r) * DKER + c * 4);
        }
        __syncthreads();
        #pragma unroll 16
        for (int tt = 0; tt < 64; ++tt) {
            float4 kk = *(const float4*)(&Ks[tt][tx * 4]);
            #pragma unroll
            for (int i = 0; i < 4; ++i) {
                float m = Ms[ty * 4 + i][tt];
                acc[i][0] += m * kk.x; acc[i][1] += m * kk.y;
                acc[i][2] += m * kk.z; acc[i][3] += m * kk.w;
            }
        }
        __syncthreads();
    }
    #pragma unroll
    for (int i = 0; i < 4; ++i) {
        float4 qv = *(const float4*)(Q2 + ((size_t)h * S + s0 + ty * 4 + i) * DKER + tx * 4);
        red[ty * 4 + i][tx] = acc[i][0] * qv.x + acc[i][1] * qv.y +
                              acc[i][2] * qv.z + acc[i][3] * qv.w;
    }
    __syncthreads();
    if (tid < 64) {
        float s = 0.f;
        #pragma unroll
        for (int j = 0; j < 16; ++j) s += red[tid][j];
        invd[(size_t)h * S + s0 + tid] = 1.f / (s + EPSF + expf(lse[(size_t)h * S + s0 + tid]));
    }
}

// Flash-style: per (h, 64-row q tile), loop t tiles of 32:
//   scores = q2abs @ k3abs^T; P = mask ? (sc+EPS)*invd : exp(w)*invd; O += P @ V
__global__ __launch_bounds__(256) void k_attn_pv(const float* __restrict__ Q2,
                                                 const float* __restrict__ K3,
                                                 const float* __restrict__ V,
                                                 const int* __restrict__ mask,
                                                 const float* __restrict__ Wsp,
                                                 const float* __restrict__ invd,
                                                 float* __restrict__ out) {
    const int h = blockIdx.y;
    const int s0 = blockIdx.x * 64;
    const int tid = threadIdx.x;
    const int ty = tid >> 4, tx = tid & 15;
    __shared__ float q2s[64][68];
    __shared__ float Ks[32][68];
    __shared__ float Vs[32][132];
    __shared__ float Ps[64][36];
    __shared__ float Wts[64][36];
    // stage q2 tile once
    #pragma unroll
    for (int it = 0; it < 4; ++it) {
        int idx = it * 256 + tid;
        int r = idx >> 4, c = idx & 15;
        *(float4*)(&q2s[r][c * 4]) =
            *(const float4*)(Q2 + ((size_t)h * S + s0 + r) * DKER + c * 4);
    }
    float id[4];
    #pragma unroll
    for (int i = 0; i < 4; ++i) id[i] = invd[(size_t)h * S + s0 + ty * 4 + i];
    float acc_o[4][8] = {};

    for (int t0 = 0; t0 < S; t0 += 32) {
        __syncthreads();  // prev-iter Ps/Vs/Ks consumers done (also covers q2s staging, iter 0)
        {   // Ks: 32x64 (2 f4/thread)
            #pragma unroll
            for (int it = 0; it < 2; ++it) {
                int idx = it * 256 + tid;
                int r = idx >> 4, c = idx & 15;
                *(float4*)(&Ks[r][c * 4]) =
                    *(const float4*)(K3 + ((size_t)h * S + t0 + r) * DKER + c * 4);
            }
            // Vs: 32x128 (4 f4/thread)
            #pragma unroll
            for (int it = 0; it < 4; ++it) {
                int idx = it * 256 + tid;
                int r = idx >> 5, c = idx & 31;
                *(float4*)(&Vs[r][c * 4]) =
                    *(const float4*)(V + (size_t)(t0 + r) * DD + h * DH + c * 4);
            }
            // Wts: 64x32 sparse-weight tile (2 f4/thread)
            #pragma unroll
            for (int it = 0; it < 2; ++it) {
                int idx = it * 256 + tid;
                int r = idx >> 3, c = idx & 7;
                *(float4*)(&Wts[r][c * 4]) =
                    *(const float4*)(Wsp + ((size_t)h * S + s0 + r) * S + t0 + c * 4);
            }
        }
        __syncthreads();
        // score tile: rows ty*4..+3, t-cols {tx, tx+16}
        float sc[4][2] = {};
        #pragma unroll 8
        for (int e = 0; e < 64; ++e) {
            float b0 = Ks[tx][e], b1 = Ks[tx + 16][e];
            #pragma unroll
            for (int i = 0; i < 4; ++i) {
                float a = q2s[ty * 4 + i][e];
                sc[i][0] += a * b0;
                sc[i][1] += a * b1;
            }
        }
        // P transform
        #pragma unroll
        for (int i = 0; i < 4; ++i) {
            int srow = s0 + ty * 4 + i;
            #pragma unroll
            for (int j = 0; j < 2; ++j) {
                int tcol = tx + j * 16;
                int m = mask[(size_t)srow * S + t0 + tcol];
                float w = Wts[ty * 4 + i][tcol];
                float p = m ? (sc[i][j] + EPSF) * id[i] : expf(w) * id[i];
                Ps[ty * 4 + i][tcol] = p;
            }
        }
        __syncthreads();
        // PV: O[rows ty*4..+3][cols tx*8..+7]
        #pragma unroll 8
        for (int tt = 0; tt < 32; ++tt) {
            float4 v0 = *(const float4*)(&Vs[tt][tx * 8]);
            float4 v1 = *(const float4*)(&Vs[tt][tx * 8 + 4]);
            #pragma unroll
            for (int i = 0; i < 4; ++i) {
                float p = Ps[ty * 4 + i][tt];
                acc_o[i][0] += p * v0.x; acc_o[i][1] += p * v0.y;
                acc_o[i][2] += p * v0.z; acc_o[i][3] += p * v0.w;
                acc_o[i][4] += p * v1.x; acc_o[i][5] += p * v1.y;
                acc_o[i][6] += p * v1.z; acc_o[i][7] += p * v1.w;
            }
        }
    }
    #pragma unroll
    for (int i = 0; i < 4; ++i) {
        float4 o0, o1;
        o0.x = acc_o[i][0]; o0.y = acc_o[i][1]; o0.z = acc_o[i][2]; o0.w = acc_o[i][3];
        o1.x = acc_o[i][4]; o1.y = acc_o[i][5]; o1.z = acc_o[i][6]; o1.w = acc_o[i][7];
        *(float4*)(out + (size_t)(s0 + ty * 4 + i) * DD + h * DH + tx * 8) = o0;
        *(float4*)(out + (size_t)(s0 + ty * 4 + i) * DD + h * DH + tx * 8 + 4) = o1;
    }
}

extern "C" void kernel_launch(void* const* d_in, const int* in_sizes, int n_in,
                              void* d_out, int out_size, void* d_ws, size_t ws_size,
                              hipStream_t stream) {
    const float* q   = (const float*)d_in[0];
    const float* k   = (const float*)d_in[1];
    const float* v   = (const float*)d_in[2];
    const int*   msk = (const int*)d_in[3];
    const float* lse = (const float*)d_in[4];
    const float* spw = (const float*)d_in[5];
    const float* wq1 = (const float*)d_in[6];
    const float* wk1 = (const float*)d_in[7];
    const float* wq2 = (const float*)d_in[8];
    const float* wk2 = (const float*)d_in[9];
    const float* ik  = (const float*)d_in[10];
    const float* sD  = (const float*)d_in[11];
    const float* sD2 = (const float*)d_in[12];
    float* out = (float*)d_out;

    float* ws = (float*)d_ws;
    float* q1   = ws;                            // NH*S*128
    float* k1   = q1 + (size_t)NH * S * DHID;    // NH*S*128
    float* q2   = k1 + (size_t)NH * S * DHID;    // NH*S*64
    float* k3   = q2 + (size_t)NH * S * DKER;    // NH*S*64
    float* invd = k3 + (size_t)NH * S * DKER;    // NH*S

    dim3 g(S / 64, NH), b(256);
    k_mlp1<<<g, b, 0, stream>>>(q, wq1, q1);
    k_mlp1<<<g, b, 0, stream>>>(k, wk1, k1);
    k_mlp2_q<<<g, b, 0, stream>>>(q1, wq2, q2);
    k_mlp2_k<<<g, b, 0, stream>>>(k1, wk2, ik, sD, sD2, k3);
    k_rowsum<<<g, b, 0, stream>>>(q2, k3, msk, lse, invd);
    k_attn_pv<<<g, b, 0, stream>>>(q2, k3, v, msk, spw, invd, out);
}

// Round 2
// 564.895 us; speedup vs baseline: 1.8661x; 1.8661x over previous
//
#include <hip/hip_runtime.h>
#include <math.h>

#define S 2048
#define DD 2048
#define NH 16
#define DH 128
#define DHID 128
#define DKER 64
#define EPSF 1e-6f

typedef __attribute__((ext_vector_type(8))) short bf16x8;
typedef __attribute__((ext_vector_type(4))) float f32x4;

__device__ __forceinline__ float gelu_f(float x) {
    return 0.5f * x * (1.0f + erff(x * 0.7071067811865475f));
}

__device__ __forceinline__ ushort f2b(float x) {
    uint32_t u = __float_as_uint(x);
    uint32_t r = (u + 0x7FFFu + ((u >> 16) & 1u)) >> 16;
    return (ushort)r;
}

// Y[h,s,e] = gelu( sum_d X[s, h*128+d] * W[h,d,e] ),  e in [0,128)  (fp32 out)
__global__ __launch_bounds__(256) void k_mlp1(const float* __restrict__ X,
                                              const float* __restrict__ Wall,
                                              float* __restrict__ Y) {
    const int h = blockIdx.y;
    const int s0 = blockIdx.x * 64;
    const int tid = threadIdx.x;
    const int ty = tid >> 4, tx = tid & 15;
    __shared__ float Xs[64][20];
    __shared__ float Ws[16][128];
    const float* Wh = Wall + h * DH * DHID;
    float acc[4][8] = {};

    const int lr = tid >> 2, lc = tid & 3;
    const int wr = tid >> 5, wc = tid & 31;
    for (int kc = 0; kc < 8; ++kc) {
        *(float4*)(&Xs[lr][lc * 4]) =
            *(const float4*)(X + (size_t)(s0 + lr) * DD + h * DH + kc * 16 + lc * 4);
        *(float4*)(&Ws[wr][wc * 4]) =
            *(const float4*)(Wh + (kc * 16 + wr) * DHID + wc * 4);
        *(float4*)(&Ws[wr + 8][wc * 4]) =
            *(const float4*)(Wh + (kc * 16 + wr + 8) * DHID + wc * 4);
        __syncthreads();
        #pragma unroll
        for (int kk = 0; kk < 16; ++kk) {
            float a[4];
            #pragma unroll
            for (int i = 0; i < 4; ++i) a[i] = Xs[ty * 4 + i][kk];
            float4 b0 = *(const float4*)(&Ws[kk][tx * 8]);
            float4 b1 = *(const float4*)(&Ws[kk][tx * 8 + 4]);
            #pragma unroll
            for (int i = 0; i < 4; ++i) {
                acc[i][0] += a[i] * b0.x; acc[i][1] += a[i] * b0.y;
                acc[i][2] += a[i] * b0.z; acc[i][3] += a[i] * b0.w;
                acc[i][4] += a[i] * b1.x; acc[i][5] += a[i] * b1.y;
                acc[i][6] += a[i] * b1.z; acc[i][7] += a[i] * b1.w;
            }
        }
        __syncthreads();
    }
    float* Yp = Y + ((size_t)h * S + s0) * DHID;
    #pragma unroll
    for (int i = 0; i < 4; ++i) {
        float4 o0, o1;
        o0.x = gelu_f(acc[i][0]); o0.y = gelu_f(acc[i][1]);
        o0.z = gelu_f(acc[i][2]); o0.w = gelu_f(acc[i][3]);
        o1.x = gelu_f(acc[i][4]); o1.y = gelu_f(acc[i][5]);
        o1.z = gelu_f(acc[i][6]); o1.w = gelu_f(acc[i][7]);
        *(float4*)(Yp + (ty * 4 + i) * DHID + tx * 8) = o0;
        *(float4*)(Yp + (ty * 4 + i) * DHID + tx * 8 + 4) = o1;
    }
}

// Q2abs[h,s,e] = | gelu( Y1[h,s,:] @ W2[h] ) |  -> bf16
__global__ __launch_bounds__(256) void k_mlp2_q(const float* __restrict__ Y1,
                                                const float* __restrict__ Wall,
                                                ushort* __restrict__ Q2) {
    const int h = blockIdx.y;
    const int s0 = blockIdx.x * 64;
    const int tid = threadIdx.x;
    const int ty = tid >> 4, tx = tid & 15;
    __shared__ float Ys[64][20];
    __shared__ float Ws[16][64];
    const float* Wh = Wall + h * DHID * DKER;
    float acc[4][4] = {};
    const int lr = tid >> 2, lc = tid & 3;
    const int wr = tid >> 4, wc = tid & 15;
    for (int kc = 0; kc < 8; ++kc) {
        *(float4*)(&Ys[lr][lc * 4]) =
            *(const float4*)(Y1 + ((size_t)h * S + s0 + lr) * DHID + kc * 16 + lc * 4);
        *(float4*)(&Ws[wr][wc * 4]) =
            *(const float4*)(Wh + (kc * 16 + wr) * DKER + wc * 4);
        __syncthreads();
        #pragma unroll
        for (int kk = 0; kk < 16; ++kk) {
            float4 b = *(const float4*)(&Ws[kk][tx * 4]);
            #pragma unroll
            for (int i = 0; i < 4; ++i) {
                float a = Ys[ty * 4 + i][kk];
                acc[i][0] += a * b.x; acc[i][1] += a * b.y;
                acc[i][2] += a * b.z; acc[i][3] += a * b.w;
            }
        }
        __syncthreads();
    }
    ushort* Qp = Q2 + ((size_t)h * S + s0) * DKER;
    #pragma unroll
    for (int i = 0; i < 4; ++i) {
        ushort4 o;
        o.x = f2b(fabsf(gelu_f(acc[i][0]))); o.y = f2b(fabsf(gelu_f(acc[i][1])));
        o.z = f2b(fabsf(gelu_f(acc[i][2]))); o.w = f2b(fabsf(gelu_f(acc[i][3])));
        *(ushort4*)(Qp + (ty * 4 + i) * DKER + tx * 4) = o;
    }
}

// k2 = |sD| * gelu(Y1k @ Wk2); K3abs = | k2 + (k2 @ Ik) * sD2 |  -> bf16
__global__ __launch_bounds__(256) void k_mlp2_k(const float* __restrict__ Y1,
                                                const float* __restrict__ Wall,
                                                const float* __restrict__ Ikall,
                                                const float* __restrict__ sD,
                                                const float* __restrict__ sD2,
                                                ushort* __restrict__ K3) {
    const int h = blockIdx.y;
    const int s0 = blockIdx.x * 64;
    const int tid = threadIdx.x;
    const int ty = tid >> 4, tx = tid & 15;
    __shared__ float Ys[64][20];
    __shared__ float Ws[16][64];
    __shared__ float K2s[64][68];
    __shared__ float Iks[64][64];
    const float* Wh = Wall + h * DHID * DKER;
    const float* Ikh = Ikall + h * DKER * DKER;
    #pragma unroll
    for (int it = 0; it < 4; ++it) {
        int idx = it * 256 + tid;
        int r = idx >> 4, c = idx & 15;
        *(float4*)(&Iks[r][c * 4]) = *(const float4*)(Ikh + r * DKER + c * 4);
    }
    float acc[4][4] = {};
    const int lr = tid >> 2, lc = tid & 3;
    const int wr = tid >> 4, wc = tid & 15;
    for (int kc = 0; kc < 8; ++kc) {
        *(float4*)(&Ys[lr][lc * 4]) =
            *(const float4*)(Y1 + ((size_t)h * S + s0 + lr) * DHID + kc * 16 + lc * 4);
        *(float4*)(&Ws[wr][wc * 4]) =
            *(const float4*)(Wh + (kc * 16 + wr) * DKER + wc * 4);
        __syncthreads();
        #pragma unroll
        for (int kk = 0; kk < 16; ++kk) {
            float4 b = *(const float4*)(&Ws[kk][tx * 4]);
            #pragma unroll
            for (int i = 0; i < 4; ++i) {
                float a = Ys[ty * 4 + i][kk];
                acc[i][0] += a * b.x; acc[i][1] += a * b.y;
                acc[i][2] += a * b.z; acc[i][3] += a * b.w;
            }
        }
        __syncthreads();
    }
    float sdv[4], sd2v[4];
    #pragma unroll
    for (int j = 0; j < 4; ++j) {
        sdv[j] = fabsf(sD[h * DKER + tx * 4 + j]);
        sd2v[j] = sD2[h * DKER + tx * 4 + j];
    }
    float k2r[4][4];
    #pragma unroll
    for (int i = 0; i < 4; ++i) {
        #pragma unroll
        for (int j = 0; j < 4; ++j) k2r[i][j] = sdv[j] * gelu_f(acc[i][j]);
        float4 o; o.x = k2r[i][0]; o.y = k2r[i][1]; o.z = k2r[i][2]; o.w = k2r[i][3];
        *(float4*)(&K2s[ty * 4 + i][tx * 4]) = o;
    }
    __syncthreads();
    float acc2[4][4] = {};
    #pragma unroll 16
    for (int f = 0; f < 64; ++f) {
        float4 b = *(const float4*)(&Iks[f][tx * 4]);
        #pragma unroll
        for (int i = 0; i < 4; ++i) {
            float a = K2s[ty * 4 + i][f];
            acc2[i][0] += a * b.x; acc2[i][1] += a * b.y;
            acc2[i][2] += a * b.z; acc2[i][3] += a * b.w;
        }
    }
    ushort* Kp = K3 + ((size_t)h * S + s0) * DKER;
    #pragma unroll
    for (int i = 0; i < 4; ++i) {
        ushort4 o;
        o.x = f2b(fabsf(k2r[i][0] + acc2[i][0] * sd2v[0]));
        o.y = f2b(fabsf(k2r[i][1] + acc2[i][1] * sd2v[1]));
        o.z = f2b(fabsf(k2r[i][2] + acc2[i][2] * sd2v[2]));
        o.w = f2b(fabsf(k2r[i][3] + acc2[i][3] * sd2v[3]));
        *(ushort4*)(Kp + (ty * 4 + i) * DKER + tx * 4) = o;
    }
}

// Vt[h][c][t] = bf16( V[t][h*128+c] )  — transpose + convert for PV B-fragments
__global__ __launch_bounds__(256) void k_vt(const float* __restrict__ V,
                                            ushort* __restrict__ Vt) {
    const int h = blockIdx.y;
    const int t0 = blockIdx.x * 64;
    const int tid = threadIdx.x;
    __shared__ ushort Ls[128][72];
    // read 64 t-rows x 128 c cols (coalesced), scatter-transpose into LDS
    #pragma unroll
    for (int it = 0; it < 8; ++it) {
        int idx = it * 256 + tid;
        int r = idx >> 5, c4 = idx & 31;           // r in [0,64), c4 in [0,32)
        float4 v = *(const float4*)(V + (size_t)(t0 + r) * DD + h * DH + c4 * 4);
        Ls[c4 * 4 + 0][r] = f2b(v.x);
        Ls[c4 * 4 + 1][r] = f2b(v.y);
        Ls[c4 * 4 + 2][r] = f2b(v.z);
        Ls[c4 * 4 + 3][r] = f2b(v.w);
    }
    __syncthreads();
    // write rows of Vt (contiguous 16B chunks)
    #pragma unroll
    for (int it = 0; it < 4; ++it) {
        int idx = it * 256 + tid;
        int row = idx >> 3, cc = idx & 7;          // row in [0,128), cc in [0,8)
        *(bf16x8*)(Vt + ((size_t)h * DH + row) * S + t0 + cc * 8) =
            *(const bf16x8*)(&Ls[row][cc * 8]);
    }
}

// Fused flash attention: scores (MFMA) -> rawP -> PV (MFMA), rowsum on the fly,
// invd normalization applied to O accumulators at the end.
__global__ __launch_bounds__(256) void k_attn(const ushort* __restrict__ Q2,
                                              const ushort* __restrict__ K3,
                                              const ushort* __restrict__ Vt,
                                              const int* __restrict__ mask,
                                              const float* __restrict__ Wsp,
                                              const float* __restrict__ lse,
                                              float* __restrict__ out) {
    const int h = blockIdx.y;
    const int s0 = blockIdx.x * 64;
    const int tid = threadIdx.x;
    const int wv = tid >> 6;           // wave 0..3 -> rows wv*16..+15
    const int lane = tid & 63;
    const int ln = lane & 15;          // C/D col & A/B m/n index
    const int quad = lane >> 4;        // C/D row group & A/B k group
    // LDS rows padded to 72 bf16 (36 dw, ≡4 mod 32 banks -> conflict-free b128 frags)
    __shared__ ushort Q2s[64][72];
    __shared__ ushort K3s[64][72];
    __shared__ ushort Vts[128][72];
    __shared__ ushort Ps[4][16][72];   // per-wave private P tile (16 rows x 64 t)

    #pragma unroll
    for (int it = 0; it < 2; ++it) {
        int idx = it * 256 + tid;
        int r = idx >> 3, c = idx & 7;
        *(bf16x8*)&Q2s[r][c * 8] =
            *(const bf16x8*)(Q2 + ((size_t)h * S + s0 + r) * DKER + c * 8);
    }

    f32x4 O[8];
    #pragma unroll
    for (int v = 0; v < 8; ++v) O[v] = (f32x4){0.f, 0.f, 0.f, 0.f};
    float rs[4] = {0.f, 0.f, 0.f, 0.f};
    const int srow_q = s0 + wv * 16 + quad * 4;   // + r gives this lane's C/D rows

    for (int t0 = 0; t0 < S; t0 += 64) {
        __syncthreads();   // previous iter's consumers done (covers Q2s staging too)
        #pragma unroll
        for (int it = 0; it < 2; ++it) {
            int idx = it * 256 + tid;
            int r = idx >> 3, c = idx & 7;
            *(bf16x8*)&K3s[r][c * 8] =
                *(const bf16x8*)(K3 + ((size_t)h * S + t0 + r) * DKER + c * 8);
        }
        #pragma unroll
        for (int it = 0; it < 4; ++it) {
            int idx = it * 256 + tid;
            int r = idx >> 3, c = idx & 7;
            *(bf16x8*)&Vts[r][c * 8] =
                *(const bf16x8*)(Vt + ((size_t)h * DH + r) * S + t0 + c * 8);
        }
        // prefetch mask & sparse weights (global, overlaps MFMA)
        int mk[4][4];
        float ww[4][4];
        #pragma unroll
        for (int n = 0; n < 4; ++n)
            #pragma unroll
            for (int r = 0; r < 4; ++r) {
                size_t off = (size_t)(srow_q + r) * S + t0 + n * 16 + ln;
                mk[n][r] = mask[off];
                ww[n][r] = Wsp[(size_t)h * S * S + off];
            }
        __syncthreads();

        // scores: (16 rows) x (64 t-cols) = Q2 @ K3^T, K=64
        f32x4 sc[4];
        #pragma unroll
        for (int n = 0; n < 4; ++n) sc[n] = (f32x4){0.f, 0.f, 0.f, 0.f};
        #pragma unroll
        for (int ks = 0; ks < 2; ++ks) {
            bf16x8 af = *(const bf16x8*)&Q2s[wv * 16 + ln][ks * 32 + quad * 8];
            #pragma unroll
            for (int n = 0; n < 4; ++n) {
                bf16x8 bf = *(const bf16x8*)&K3s[n * 16 + ln][ks * 32 + quad * 8];
                sc[n] = __builtin_amdgcn_mfma_f32_16x16x32_bf16(af, bf, sc[n], 0, 0, 0);
            }
        }
        // P transform (C-layout: row = quad*4+r, col = n*16+ln), accumulate rowsum
        #pragma unroll
        for (int n = 0; n < 4; ++n)
            #pragma unroll
            for (int r = 0; r < 4; ++r) {
                float s = sc[n][r];
                float p;
                if (mk[n][r]) { rs[r] += s; p = s + EPSF; }
                else          { p = expf(ww[n][r]); }
                Ps[wv][quad * 4 + r][n * 16 + ln] = f2b(p);
            }
        // PV: O(16x128) += P(16x64) @ V(64x128). Same-wave LDS dep: compiler waits.
        #pragma unroll
        for (int ks = 0; ks < 2; ++ks) {
            bf16x8 pf = *(const bf16x8*)&Ps[wv][ln][ks * 32 + quad * 8];
            #pragma unroll
            for (int v = 0; v < 8; ++v) {
                bf16x8 vf = *(const bf16x8*)&Vts[v * 16 + ln][ks * 32 + quad * 8];
                O[v] = __builtin_amdgcn_mfma_f32_16x16x32_bf16(pf, vf, O[v], 0, 0, 0);
            }
        }
    }
    // reduce rowsum across the 16 lanes sharing each C/D row (xor<16 stays in quad)
    #pragma unroll
    for (int r = 0; r < 4; ++r) {
        float v = rs[r];
        v += __shfl_xor(v, 1); v += __shfl_xor(v, 2);
        v += __shfl_xor(v, 4); v += __shfl_xor(v, 8);
        rs[r] = v;
    }
    float idv[4];
    #pragma unroll
    for (int r = 0; r < 4; ++r)
        idv[r] = 1.f / (rs[r] + EPSF + expf(lse[(size_t)h * S + srow_q + r]));
    #pragma unroll
    for (int v = 0; v < 8; ++v)
        #pragma unroll
        for (int r = 0; r < 4; ++r)
            out[(size_t)(srow_q + r) * DD + h * DH + v * 16 + ln] = O[v][r] * idv[r];
}

extern "C" void kernel_launch(void* const* d_in, const int* in_sizes, int n_in,
                              void* d_out, int out_size, void* d_ws, size_t ws_size,
                              hipStream_t stream) {
    const float* q   = (const float*)d_in[0];
    const float* k   = (const float*)d_in[1];
    const float* v   = (const float*)d_in[2];
    const int*   msk = (const int*)d_in[3];
    const float* lse = (const float*)d_in[4];
    const float* spw = (const float*)d_in[5];
    const float* wq1 = (const float*)d_in[6];
    const float* wk1 = (const float*)d_in[7];
    const float* wq2 = (const float*)d_in[8];
    const float* wk2 = (const float*)d_in[9];
    const float* ik  = (const float*)d_in[10];
    const float* sD  = (const float*)d_in[11];
    const float* sD2 = (const float*)d_in[12];
    float* out = (float*)d_out;

    float* ws = (float*)d_ws;
    float*  q1  = ws;                                  // 16*2048*128 f32
    float*  k1  = q1 + (size_t)NH * S * DHID;          // 16*2048*128 f32
    ushort* q2b = (ushort*)(k1 + (size_t)NH * S * DHID);   // 16*2048*64 bf16
    ushort* k3b = q2b + (size_t)NH * S * DKER;             // 16*2048*64 bf16
    ushort* vt  = k3b + (size_t)NH * S * DKER;             // 16*128*2048 bf16

    dim3 g(S / 64, NH), b(256);
    k_mlp1<<<g, b, 0, stream>>>(q, wq1, q1);
    k_mlp1<<<g, b, 0, stream>>>(k, wk1, k1);
    k_mlp2_q<<<g, b, 0, stream>>>(q1, wq2, q2b);
    k_mlp2_k<<<g, b, 0, stream>>>(k1, wk2, ik, sD, sD2, k3b);
    k_vt<<<g, b, 0, stream>>>(v, vt);
    k_attn<<<g, b, 0, stream>>>(q2b, k3b, vt, msk, spw, lse, out);
}